// Round 9
// baseline (548.665 us; speedup 1.0000x reference)
//
#include <hip/hip_runtime.h>
#include <hip/hip_bf16.h>
#include <math.h>

typedef __bf16 bf16x8 __attribute__((ext_vector_type(8)));
typedef __bf16 bf16x4 __attribute__((ext_vector_type(4)));
typedef float f32x4 __attribute__((ext_vector_type(4)));

#define MFMA_BF16 __builtin_amdgcn_mfma_f32_16x16x32_bf16

// softmax scale 1/8 folded with log2(e): sv = (q.k)/8*log2e, p = exp2(sv)
#define QSCALE 0.18033688011112042f

__device__ inline void async_load16(const __hip_bfloat16* g, __hip_bfloat16* l) {
    __builtin_amdgcn_global_load_lds(
        (const __attribute__((address_space(1))) unsigned int*)g,
        (__attribute__((address_space(3))) unsigned int*)l,
        16, 0, 0);
}

// swap bits 2<->3 (row permutation for K staging; involution)
__device__ inline int sig(int x) {
    return (x & ~12) | ((x & 4) << 1) | ((x & 8) >> 1);
}

// pack two f32 into (bf16(lo), bf16(hi)) dword by truncation — 1 v_perm_b32
__device__ inline unsigned int pack_bf16_trunc(float lo, float hi) {
    return __builtin_amdgcn_perm(__float_as_uint(hi), __float_as_uint(lo),
                                 0x07060302u);
}

// ---------- one-shot fp32->bf16 for x and the 4 weight matrices ----------
__global__ __launch_bounds__(256) void convert_all(
    const float* __restrict__ x,
    const float* __restrict__ Wq, const float* __restrict__ Wk,
    const float* __restrict__ Wv, const float* __restrict__ Wp,
    __hip_bfloat16* __restrict__ xb,
    __hip_bfloat16* __restrict__ Wqb, __hip_bfloat16* __restrict__ Wkb,
    __hip_bfloat16* __restrict__ Wvb, __hip_bfloat16* __restrict__ Wpb,
    int nx, int nw)
{
    const int xblocks = nx >> 11;   // /(256*8)
    const int wblocks = nw >> 11;
    int b = blockIdx.x;
    const float* in;
    __hip_bfloat16* out;
    int i;
    if (b < xblocks) {
        in = x; out = xb; i = (b * 256 + threadIdx.x) * 8;
    } else {
        b -= xblocks;
        const int w = b / wblocks, bb = b - w * wblocks;
        in  = w == 0 ? Wq : w == 1 ? Wk : w == 2 ? Wv : Wp;
        out = w == 0 ? Wqb : w == 1 ? Wkb : w == 2 ? Wvb : Wpb;
        i = (bb * 256 + threadIdx.x) * 8;
    }
    const float4 a = *(const float4*)(in + i);
    const float4 c = *(const float4*)(in + i + 4);
    __hip_bfloat16 tmp[8];
    tmp[0] = __float2bfloat16(a.x); tmp[1] = __float2bfloat16(a.y);
    tmp[2] = __float2bfloat16(a.z); tmp[3] = __float2bfloat16(a.w);
    tmp[4] = __float2bfloat16(c.x); tmp[5] = __float2bfloat16(c.y);
    tmp[6] = __float2bfloat16(c.z); tmp[7] = __float2bfloat16(c.w);
    *(bf16x8*)(out + i) = *(const bf16x8*)tmp;
}

// ---------------- fused QKV GEMM, BK=64, swizzled LDS ----------------
// sel==2 (V) blocks transpose their 128x128 output tile through LDS and
// write V^T (C x M) directly — no separate transpose kernel.
__global__ __launch_bounds__(256) void gemm_qkv(
    const __hip_bfloat16* __restrict__ A,
    const __hip_bfloat16* __restrict__ B,
    const float* __restrict__ bq, const float* __restrict__ bk, const float* __restrict__ bv,
    __hip_bfloat16* __restrict__ Qo, __hip_bfloat16* __restrict__ Ko,
    __hip_bfloat16* __restrict__ Vt,
    int M, int K)
{
    __shared__ __align__(16) __hip_bfloat16 smem[2 * 128 * 64];
    __hip_bfloat16* As = smem;
    __hip_bfloat16* Bs = smem + 128 * 64;

    const int tid  = threadIdx.x;
    const int lane = tid & 63;
    const int wave = tid >> 6;
    const int l15  = lane & 15;
    const int quad = lane >> 4;
    const int m0 = blockIdx.x * 128;
    const int n0 = blockIdx.y * 128;
    const int wr = wave >> 1, wc = wave & 1;
    const int sel = n0 >> 10;     // 0=Q 1=K 2=V, block-uniform

    f32x4 acc[4][4] = {};

    int srow[4], scol[4];
    #pragma unroll
    for (int i = 0; i < 4; ++i) {
        const int c = tid + 256 * i;
        srow[i] = c >> 3;
        scol[i] = ((c & 7) ^ (srow[i] & 7)) * 8;
    }

    for (int k0 = 0; k0 < K; k0 += 64) {
        __syncthreads();
        #pragma unroll
        for (int i = 0; i < 4; ++i) {
            async_load16(A + (size_t)(m0 + srow[i]) * K + k0 + scol[i],
                         As + (size_t)(tid + 256 * i) * 8);
            async_load16(B + (size_t)(n0 + srow[i]) * K + k0 + scol[i],
                         Bs + (size_t)(tid + 256 * i) * 8);
        }
        __syncthreads();

        #pragma unroll
        for (int kd = 0; kd < 2; ++kd) {
            bf16x8 af[4], bfr[4];
            #pragma unroll
            for (int mi = 0; mi < 4; ++mi) {
                const int row = wr * 64 + mi * 16 + l15;
                af[mi] = *(const bf16x8*)(
                    As + row * 64 + (((kd * 4 + quad) ^ (row & 7)) << 3));
            }
            #pragma unroll
            for (int ni = 0; ni < 4; ++ni) {
                const int row = wc * 64 + ni * 16 + l15;
                bfr[ni] = *(const bf16x8*)(
                    Bs + row * 64 + (((kd * 4 + quad) ^ (row & 7)) << 3));
            }
            #pragma unroll
            for (int mi = 0; mi < 4; ++mi)
                #pragma unroll
                for (int ni = 0; ni < 4; ++ni)
                    acc[mi][ni] = MFMA_BF16(af[mi], bfr[ni], acc[mi][ni], 0, 0, 0);
        }
    }

    if (sel == 2) {
        // ---- V: transpose 128x128 tile through LDS, write V^T coalesced ----
        __syncthreads();   // main-loop LDS reads complete
        #pragma unroll
        for (int ni = 0; ni < 4; ++ni) {
            const int lc = wc * 64 + ni * 16 + l15;        // local channel
            const float bias = bv[(n0 + lc) & 1023];
            #pragma unroll
            for (int mi = 0; mi < 4; ++mi) {
                const int mb = wr * 64 + mi * 16 + quad * 4;   // local token base
                const int g = mb >> 3, off = mb & 7;
                __hip_bfloat16 t[4];
                #pragma unroll
                for (int r = 0; r < 4; ++r)
                    t[r] = __float2bfloat16(acc[mi][ni][r] + bias);
                *(bf16x4*)(smem + lc * 128 + ((g ^ (lc & 15)) << 3) + off)
                    = *(const bf16x4*)t;
            }
        }
        __syncthreads();
        const int cc0 = n0 & 1023;
        #pragma unroll
        for (int i = 0; i < 8; ++i) {
            const int q = tid + 256 * i;          // 2048 16B chunks
            const int ch = q >> 4, mg = q & 15;
            bf16x8 v = *(const bf16x8*)(smem + ch * 128 + ((mg ^ (ch & 15)) << 3));
            *(bf16x8*)(Vt + (size_t)(cc0 + ch) * M + m0 + mg * 8) = v;
        }
    } else {
        __hip_bfloat16* dst = sel == 0 ? Qo : Ko;
        const float* bptr   = sel == 0 ? bq : bk;
        const float sc      = sel == 0 ? QSCALE : 1.0f;
        #pragma unroll
        for (int ni = 0; ni < 4; ++ni) {
            const int cc = (n0 + wc * 64 + ni * 16 + l15) & 1023;
            const float bias = bptr[cc];
            #pragma unroll
            for (int mi = 0; mi < 4; ++mi) {
                const int row = m0 + wr * 64 + mi * 16 + quad * 4;
                #pragma unroll
                for (int r = 0; r < 4; ++r)
                    dst[(size_t)(row + r) * 1024 + cc] =
                        __float2bfloat16((acc[mi][ni][r] + bias) * sc);
            }
        }
    }
}

// ---------------- out-proj GEMM (fp32 out), 64x128 tile, BK=64 ----------------
__global__ __launch_bounds__(256) void gemm_out_f32(
    const __hip_bfloat16* __restrict__ A,
    const __hip_bfloat16* __restrict__ B,
    const float* __restrict__ bias,
    float* __restrict__ Cf,
    int M, int N, int K)
{
    __shared__ __align__(16) __hip_bfloat16 As[64 * 64];
    __shared__ __align__(16) __hip_bfloat16 Bs[128 * 64];

    const int tid  = threadIdx.x;
    const int lane = tid & 63;
    const int wave = tid >> 6;
    const int l15  = lane & 15;
    const int quad = lane >> 4;
    const int m0 = blockIdx.x * 64;
    const int n0 = blockIdx.y * 128;
    const int wr = wave >> 1, wc = wave & 1;   // wave tile: 32 x 64

    f32x4 acc[2][4] = {};

    int srow[4], scol[4];
    #pragma unroll
    for (int i = 0; i < 4; ++i) {
        const int c = tid + 256 * i;
        srow[i] = c >> 3;
        scol[i] = ((c & 7) ^ (srow[i] & 7)) * 8;
    }

    for (int k0 = 0; k0 < K; k0 += 64) {
        __syncthreads();
        #pragma unroll
        for (int i = 0; i < 2; ++i)
            async_load16(A + (size_t)(m0 + srow[i]) * K + k0 + scol[i],
                         As + (size_t)(tid + 256 * i) * 8);
        #pragma unroll
        for (int i = 0; i < 4; ++i)
            async_load16(B + (size_t)(n0 + srow[i]) * K + k0 + scol[i],
                         Bs + (size_t)(tid + 256 * i) * 8);
        __syncthreads();

        #pragma unroll
        for (int kd = 0; kd < 2; ++kd) {
            bf16x8 af[2], bfr[4];
            #pragma unroll
            for (int mi = 0; mi < 2; ++mi) {
                const int row = wr * 32 + mi * 16 + l15;
                af[mi] = *(const bf16x8*)(
                    As + row * 64 + (((kd * 4 + quad) ^ (row & 7)) << 3));
            }
            #pragma unroll
            for (int ni = 0; ni < 4; ++ni) {
                const int row = wc * 64 + ni * 16 + l15;
                bfr[ni] = *(const bf16x8*)(
                    Bs + row * 64 + (((kd * 4 + quad) ^ (row & 7)) << 3));
            }
            #pragma unroll
            for (int mi = 0; mi < 2; ++mi)
                #pragma unroll
                for (int ni = 0; ni < 4; ++ni)
                    acc[mi][ni] = MFMA_BF16(af[mi], bfr[ni], acc[mi][ni], 0, 0, 0);
        }
    }

    #pragma unroll
    for (int ni = 0; ni < 4; ++ni) {
        const int col = n0 + wc * 64 + ni * 16 + l15;
        const float bv = bias[col];
        #pragma unroll
        for (int mi = 0; mi < 2; ++mi) {
            const int row = m0 + wr * 32 + mi * 16 + quad * 4;
            #pragma unroll
            for (int r = 0; r < 4; ++r)
                Cf[(size_t)(row + r) * N + col] = acc[mi][ni][r] + bv;
        }
    }
}

// ------- flash attention: balanced pair + quarter-split + fused merge -------
// Block = (pair j, quarter sq, head h): 17 iters of 64 keys, uniform grid.
// Partials per quarter; the 4th block to finish a (tile,head) merges all 4
// partials into Y (device-scope atomic counter + fences). Y aliases Q: safe,
// only the 4 finished blocks of that (tile,head) ever read those Q elements.
__global__ __launch_bounds__(512, 4) void attn_causal(
    const __hip_bfloat16* __restrict__ Q,
    const __hip_bfloat16* __restrict__ K,
    const __hip_bfloat16* __restrict__ Vt,
    __hip_bfloat16* __restrict__ PoB,   // [4][T*C]
    float* __restrict__ PlB,            // [4][16*T]
    int* __restrict__ cnt,              // [16 tiles][16 heads], zeroed
    __hip_bfloat16* __restrict__ Y,
    int T, int C)
{
    const int h  = blockIdx.y;
    const int bx = blockIdx.x;          // [0,32)
    const int j  = bx & 7;              // pair index
    const int sq = bx >> 3;             // quarter [0,4)
    const int tid  = threadIdx.x;
    const int w    = tid >> 6;
    const int lane = tid & 63;
    const int l15  = lane & 15;
    const int quad = lane >> 4;

    const size_t TCs = (size_t)T * C;
    const size_t HT  = (size_t)T * 16;
    __hip_bfloat16* Po = PoB + (size_t)sq * TCs;
    float* Pl = PlB + (size_t)sq * HT;

    const int len1 = j + 1, len2 = 16 - j;
    const int tile1 = j,    tile2 = 15 - j;
    const int kb1 = len1 * sq, kb2 = len2 * sq;

    __shared__ __align__(16) __hip_bfloat16 Ks[2][64 * 64];
    __shared__ __align__(16) __hip_bfloat16 Vts[2][64 * 64];
    __shared__ int wonFlags[2];

    const int r0 = tid >> 3, g0 = ((tid & 7) ^ (r0 & 7)) * 8;
    const __hip_bfloat16* Kg0 = K + (size_t)sig(r0) * C + h * 64 + g0;
    const __hip_bfloat16* Vg0 = Vt + (size_t)(h * 64 + r0) * T + g0;

    int koff[2][4], voff[2][4];
    #pragma unroll
    for (int kd = 0; kd < 2; ++kd)
        #pragma unroll
        for (int sb = 0; sb < 4; ++sb) {
            const int kappa = 32 * (sb & 1) + 8 * (l15 >> 2) + 4 * (sb >> 1) + (l15 & 3);
            const int rho = sig(kappa);
            koff[kd][sb] = rho * 64 + (((kd * 4 + quad) ^ (rho & 7)) << 3);
        }
    #pragma unroll
    for (int kk = 0; kk < 2; ++kk)
        #pragma unroll
        for (int db = 0; db < 4; ++db) {
            const int vrow = db * 16 + l15;
            voff[kk][db] = vrow * 64 + (((kk * 4 + quad) ^ (vrow & 7)) << 3);
        }

    bf16x8 ones;
    #pragma unroll
    for (int jj = 0; jj < 8; ++jj) ones[jj] = (__bf16)1.0f;

    int qbase = tile1 * 256 + w * 32;
    bf16x8 aq[2][2];
    #pragma unroll
    for (int rb = 0; rb < 2; ++rb)
        #pragma unroll
        for (int kd = 0; kd < 2; ++kd)
            aq[rb][kd] = *(const bf16x8*)(
                Q + (size_t)(qbase + rb * 16 + l15) * C + h * 64 + kd * 32 + quad * 8);

    f32x4 o[2][4] = {};
    f32x4 lacc[2] = {};

    {
        const size_t so = (size_t)kb1 << 6;
        async_load16(Kg0 + so * C, &Ks[0][tid * 8]);
        async_load16(Vg0 + so, &Vts[0][tid * 8]);
    }

    for (int it = 0; it < 17; ++it) {
        const int kb = (it < len1) ? (kb1 + it) : (kb2 + it - len1);
        const int s0 = kb << 6;
        __syncthreads();
        const int cur = it & 1;
        if (it + 1 < 17) {
            const int kbn = (it + 1 < len1) ? (kb1 + it + 1) : (kb2 + it + 1 - len1);
            const size_t so = (size_t)kbn << 6;
            async_load16(Kg0 + so * C, &Ks[cur ^ 1][tid * 8]);
            async_load16(Vg0 + so, &Vts[cur ^ 1][tid * 8]);
        }

        if (it == len1) {
            // flush phase-1 partials, count, switch to tile2
            #pragma unroll
            for (int rb = 0; rb < 2; ++rb) {
                const int row = qbase + rb * 16 + l15;
                #pragma unroll
                for (int db = 0; db < 4; ++db) {
                    __hip_bfloat16 t[4];
                    #pragma unroll
                    for (int r = 0; r < 4; ++r)
                        t[r] = __float2bfloat16(o[rb][db][r]);
                    *(bf16x4*)(Po + (size_t)row * C + h * 64 + db * 16 + quad * 4)
                        = *(const bf16x4*)t;
                    o[rb][db] = (f32x4){0.f, 0.f, 0.f, 0.f};
                }
                if (quad == 0)
                    Pl[(size_t)h * T + row] = lacc[rb][0];
                lacc[rb] = (f32x4){0.f, 0.f, 0.f, 0.f};
            }
            __threadfence();
            __syncthreads();
            if (tid == 0)
                wonFlags[0] = (atomicAdd(&cnt[tile1 * 16 + h], 1) == 3);
            qbase = tile2 * 256 + w * 32;
            #pragma unroll
            for (int rb = 0; rb < 2; ++rb)
                #pragma unroll
                for (int kd = 0; kd < 2; ++kd)
                    aq[rb][kd] = *(const bf16x8*)(
                        Q + (size_t)(qbase + rb * 16 + l15) * C + h * 64 + kd * 32 + quad * 8);
        }

        if (s0 <= qbase + 31) {
            f32x4 sv[2][4] = {};
            #pragma unroll
            for (int kd = 0; kd < 2; ++kd)
                #pragma unroll
                for (int sb = 0; sb < 4; ++sb) {
                    bf16x8 ak = *(const bf16x8*)(&Ks[cur][koff[kd][sb]]);
                    sv[0][sb] = MFMA_BF16(ak, aq[0][kd], sv[0][sb], 0, 0, 0);
                    sv[1][sb] = MFMA_BF16(ak, aq[1][kd], sv[1][sb], 0, 0, 0);
                }

            const bool diag = (s0 + 63 > qbase);
            bf16x8 bp[2][2];
            #pragma unroll
            for (int rb = 0; rb < 2; ++rb) {
                float pv[4][4];
                #pragma unroll
                for (int sb = 0; sb < 4; ++sb)
                    #pragma unroll
                    for (int r = 0; r < 4; ++r)
                        pv[sb][r] = __builtin_amdgcn_exp2f(sv[rb][sb][r]);
                if (diag) {
                    const int thr = qbase + rb * 16 + l15 - s0 - 8 * quad;
                    #pragma unroll
                    for (int sb = 0; sb < 4; ++sb)
                        #pragma unroll
                        for (int r = 0; r < 4; ++r) {
                            const int c = 32 * (sb & 1) + 4 * (sb >> 1) + r;
                            pv[sb][r] = (c <= thr) ? pv[sb][r] : 0.f;
                        }
                }
                #pragma unroll
                for (int kk = 0; kk < 2; ++kk) {
                    union { unsigned int u[4]; bf16x8 v; } pk;
                    pk.u[0] = pack_bf16_trunc(pv[kk][0], pv[kk][1]);
                    pk.u[1] = pack_bf16_trunc(pv[kk][2], pv[kk][3]);
                    pk.u[2] = pack_bf16_trunc(pv[kk + 2][0], pv[kk + 2][1]);
                    pk.u[3] = pack_bf16_trunc(pv[kk + 2][2], pv[kk + 2][3]);
                    bp[rb][kk] = pk.v;
                }
            }

            lacc[0] = MFMA_BF16(ones, bp[0][0], lacc[0], 0, 0, 0);
            lacc[0] = MFMA_BF16(ones, bp[0][1], lacc[0], 0, 0, 0);
            lacc[1] = MFMA_BF16(ones, bp[1][0], lacc[1], 0, 0, 0);
            lacc[1] = MFMA_BF16(ones, bp[1][1], lacc[1], 0, 0, 0);

            #pragma unroll
            for (int kk = 0; kk < 2; ++kk)
                #pragma unroll
                for (int db = 0; db < 4; ++db) {
                    bf16x8 av = *(const bf16x8*)(&Vts[cur][voff[kk][db]]);
                    o[0][db] = MFMA_BF16(av, bp[0][kk], o[0][db], 0, 0, 0);
                    o[1][db] = MFMA_BF16(av, bp[1][kk], o[1][db], 0, 0, 0);
                }
        }
    }

    // final flush (tile2) + count
    #pragma unroll
    for (int rb = 0; rb < 2; ++rb) {
        const int row = qbase + rb * 16 + l15;
        #pragma unroll
        for (int db = 0; db < 4; ++db) {
            __hip_bfloat16 t[4];
            #pragma unroll
            for (int r = 0; r < 4; ++r)
                t[r] = __float2bfloat16(o[rb][db][r]);
            *(bf16x4*)(Po + (size_t)row * C + h * 64 + db * 16 + quad * 4)
                = *(const bf16x4*)t;
        }
        if (quad == 0)
            Pl[(size_t)h * T + row] = lacc[rb][0];
    }
    __threadfence();
    __syncthreads();
    if (tid == 0)
        wonFlags[1] = (atomicAdd(&cnt[tile2 * 16 + h], 1) == 3);
    __syncthreads();

    // merge any (tile,head) this block closed out
    #pragma unroll
    for (int e = 0; e < 2; ++e) {
        const int tl = e == 0 ? tile1 : tile2;
        if (wonFlags[e]) {
            __threadfence();   // acquire: other quarters' partials visible
            #pragma unroll
            for (int i = 0; i < 4; ++i) {
                const int qc = tid + 512 * i;          // 2048 16B chunks
                const int r  = qc >> 3;
                const int c8 = (qc & 7) * 8;
                const int row = tl * 256 + r;
                const size_t base = (size_t)row * C + h * 64 + c8;
                float a8[8] = {};
                float l = 0.f;
                #pragma unroll
                for (int z = 0; z < 4; ++z) {
                    bf16x8 a = *(const bf16x8*)(PoB + (size_t)z * TCs + base);
                    #pragma unroll
                    for (int rr = 0; rr < 8; ++rr)
                        a8[rr] += (float)(((const __bf16*)&a)[rr]);
                    l += PlB[(size_t)z * HT + (size_t)h * T + row];
                }
                const float inv = 1.0f / l;
                __hip_bfloat16 t[8];
                #pragma unroll
                for (int rr = 0; rr < 8; ++rr)
                    t[rr] = __float2bfloat16(a8[rr] * inv);
                *(bf16x8*)(Y + base) = *(const bf16x8*)t;
            }
        }
    }
}

extern "C" void kernel_launch(void* const* d_in, const int* in_sizes, int n_in,
                              void* d_out, int out_size, void* d_ws, size_t ws_size,
                              hipStream_t stream)
{
    const float* x  = (const float*)d_in[0];
    const float* Wq = (const float*)d_in[1];
    const float* bq = (const float*)d_in[2];
    const float* Wk = (const float*)d_in[3];
    const float* bk = (const float*)d_in[4];
    const float* Wv = (const float*)d_in[5];
    const float* bv = (const float*)d_in[6];
    const float* Wp = (const float*)d_in[7];
    const float* bp = (const float*)d_in[8];

    const int C = 1024;
    const int T = in_sizes[0] / C;   // 4096
    const int H = 16;
    const size_t TC = (size_t)T * C;
    const size_t CC = (size_t)C * C;

    // ws (bf16 elems): xb | W4 | Q | K | Vt | Po[4] | Pl[4] (f32) | cnt (int)
    __hip_bfloat16* xb  = (__hip_bfloat16*)d_ws;
    __hip_bfloat16* Wqb = xb + TC;
    __hip_bfloat16* Wkb = Wqb + CC;
    __hip_bfloat16* Wvb = Wkb + CC;
    __hip_bfloat16* Wpb = Wvb + CC;
    __hip_bfloat16* Qw  = Wpb + CC;
    __hip_bfloat16* Kw  = Qw + TC;
    __hip_bfloat16* Vtw = Kw + TC;
    __hip_bfloat16* PoB = Vtw + TC;          // 4 * TC bf16
    float* PlB = (float*)(PoB + 4 * TC);     // 4 * 16*T fp32
    int* cnt = (int*)(PlB + 4 * (size_t)T * 16);  // 256 ints
    __hip_bfloat16* Yw  = Qw;                // alias: Q dead per (tile,head) at merge
    float* out = (float*)d_out;

    convert_all<<<(int)(TC / 2048 + 4 * CC / 2048), 256, 0, stream>>>(
        x, Wq, Wk, Wv, Wp, xb, Wqb, Wkb, Wvb, Wpb, (int)TC, (int)CC);

    gemm_qkv<<<dim3(T / 128, 3072 / 128), 256, 0, stream>>>(
        xb, Wqb, bq, bk, bv, Qw, Kw, Vtw, T, C);

    hipMemsetAsync(cnt, 0, 16 * 16 * sizeof(int), stream);

    attn_causal<<<dim3(32, H), 512, 0, stream>>>(
        Qw, Kw, Vtw, PoB, PlB, cnt, Yw, T, C);

    gemm_out_f32<<<dim3(T / 64, C / 128), 256, 0, stream>>>(
        Yw, Wpb, bp, out, T, C, C);
}

// Round 10
// 201.497 us; speedup vs baseline: 2.7229x; 2.7229x over previous
//
#include <hip/hip_runtime.h>
#include <hip/hip_bf16.h>
#include <math.h>

typedef __bf16 bf16x8 __attribute__((ext_vector_type(8)));
typedef __bf16 bf16x4 __attribute__((ext_vector_type(4)));
typedef float f32x4 __attribute__((ext_vector_type(4)));

#define MFMA_BF16 __builtin_amdgcn_mfma_f32_16x16x32_bf16

// softmax scale 1/8 folded with log2(e): sv = (q.k)/8*log2e, p = exp2(sv)
#define QSCALE 0.18033688011112042f

__device__ inline void async_load16(const __hip_bfloat16* g, __hip_bfloat16* l) {
    __builtin_amdgcn_global_load_lds(
        (const __attribute__((address_space(1))) unsigned int*)g,
        (__attribute__((address_space(3))) unsigned int*)l,
        16, 0, 0);
}

// swap bits 2<->3 (row permutation for K staging; involution)
__device__ inline int sig(int x) {
    return (x & ~12) | ((x & 4) << 1) | ((x & 8) >> 1);
}

// pack two f32 into (bf16(lo), bf16(hi)) dword by truncation — 1 v_perm_b32
__device__ inline unsigned int pack_bf16_trunc(float lo, float hi) {
    return __builtin_amdgcn_perm(__float_as_uint(hi), __float_as_uint(lo),
                                 0x07060302u);
}

// ---------- one-shot fp32->bf16 for x and the 4 weight matrices ----------
__global__ __launch_bounds__(256) void convert_all(
    const float* __restrict__ x,
    const float* __restrict__ Wq, const float* __restrict__ Wk,
    const float* __restrict__ Wv, const float* __restrict__ Wp,
    __hip_bfloat16* __restrict__ xb,
    __hip_bfloat16* __restrict__ Wqb, __hip_bfloat16* __restrict__ Wkb,
    __hip_bfloat16* __restrict__ Wvb, __hip_bfloat16* __restrict__ Wpb,
    int nx, int nw)
{
    const int xblocks = nx >> 11;   // /(256*8)
    const int wblocks = nw >> 11;
    int b = blockIdx.x;
    const float* in;
    __hip_bfloat16* out;
    int i;
    if (b < xblocks) {
        in = x; out = xb; i = (b * 256 + threadIdx.x) * 8;
    } else {
        b -= xblocks;
        const int w = b / wblocks, bb = b - w * wblocks;
        in  = w == 0 ? Wq : w == 1 ? Wk : w == 2 ? Wv : Wp;
        out = w == 0 ? Wqb : w == 1 ? Wkb : w == 2 ? Wvb : Wpb;
        i = (bb * 256 + threadIdx.x) * 8;
    }
    const float4 a = *(const float4*)(in + i);
    const float4 c = *(const float4*)(in + i + 4);
    __hip_bfloat16 tmp[8];
    tmp[0] = __float2bfloat16(a.x); tmp[1] = __float2bfloat16(a.y);
    tmp[2] = __float2bfloat16(a.z); tmp[3] = __float2bfloat16(a.w);
    tmp[4] = __float2bfloat16(c.x); tmp[5] = __float2bfloat16(c.y);
    tmp[6] = __float2bfloat16(c.z); tmp[7] = __float2bfloat16(c.w);
    *(bf16x8*)(out + i) = *(const bf16x8*)tmp;
}

// ---------------- fused QKV GEMM, BK=64, swizzled LDS ----------------
// sel==2 (V) blocks transpose their 128x128 output tile through LDS and
// write V^T (C x M) directly — no separate transpose kernel.
__global__ __launch_bounds__(256) void gemm_qkv(
    const __hip_bfloat16* __restrict__ A,
    const __hip_bfloat16* __restrict__ B,
    const float* __restrict__ bq, const float* __restrict__ bk, const float* __restrict__ bv,
    __hip_bfloat16* __restrict__ Qo, __hip_bfloat16* __restrict__ Ko,
    __hip_bfloat16* __restrict__ Vt,
    int M, int K)
{
    __shared__ __align__(16) __hip_bfloat16 smem[2 * 128 * 64];
    __hip_bfloat16* As = smem;
    __hip_bfloat16* Bs = smem + 128 * 64;

    const int tid  = threadIdx.x;
    const int lane = tid & 63;
    const int wave = tid >> 6;
    const int l15  = lane & 15;
    const int quad = lane >> 4;
    const int m0 = blockIdx.x * 128;
    const int n0 = blockIdx.y * 128;
    const int wr = wave >> 1, wc = wave & 1;
    const int sel = n0 >> 10;     // 0=Q 1=K 2=V, block-uniform

    f32x4 acc[4][4] = {};

    int srow[4], scol[4];
    #pragma unroll
    for (int i = 0; i < 4; ++i) {
        const int c = tid + 256 * i;
        srow[i] = c >> 3;
        scol[i] = ((c & 7) ^ (srow[i] & 7)) * 8;
    }

    for (int k0 = 0; k0 < K; k0 += 64) {
        __syncthreads();
        #pragma unroll
        for (int i = 0; i < 4; ++i) {
            async_load16(A + (size_t)(m0 + srow[i]) * K + k0 + scol[i],
                         As + (size_t)(tid + 256 * i) * 8);
            async_load16(B + (size_t)(n0 + srow[i]) * K + k0 + scol[i],
                         Bs + (size_t)(tid + 256 * i) * 8);
        }
        __syncthreads();

        #pragma unroll
        for (int kd = 0; kd < 2; ++kd) {
            bf16x8 af[4], bfr[4];
            #pragma unroll
            for (int mi = 0; mi < 4; ++mi) {
                const int row = wr * 64 + mi * 16 + l15;
                af[mi] = *(const bf16x8*)(
                    As + row * 64 + (((kd * 4 + quad) ^ (row & 7)) << 3));
            }
            #pragma unroll
            for (int ni = 0; ni < 4; ++ni) {
                const int row = wc * 64 + ni * 16 + l15;
                bfr[ni] = *(const bf16x8*)(
                    Bs + row * 64 + (((kd * 4 + quad) ^ (row & 7)) << 3));
            }
            #pragma unroll
            for (int mi = 0; mi < 4; ++mi)
                #pragma unroll
                for (int ni = 0; ni < 4; ++ni)
                    acc[mi][ni] = MFMA_BF16(af[mi], bfr[ni], acc[mi][ni], 0, 0, 0);
        }
    }

    if (sel == 2) {
        // ---- V: transpose 128x128 tile through LDS, write V^T coalesced ----
        __syncthreads();   // main-loop LDS reads complete
        #pragma unroll
        for (int ni = 0; ni < 4; ++ni) {
            const int lc = wc * 64 + ni * 16 + l15;        // local channel
            const float bias = bv[(n0 + lc) & 1023];
            #pragma unroll
            for (int mi = 0; mi < 4; ++mi) {
                const int mb = wr * 64 + mi * 16 + quad * 4;   // local token base
                const int g = mb >> 3, off = mb & 7;
                __hip_bfloat16 t[4];
                #pragma unroll
                for (int r = 0; r < 4; ++r)
                    t[r] = __float2bfloat16(acc[mi][ni][r] + bias);
                *(bf16x4*)(smem + lc * 128 + ((g ^ (lc & 15)) << 3) + off)
                    = *(const bf16x4*)t;
            }
        }
        __syncthreads();
        const int cc0 = n0 & 1023;
        #pragma unroll
        for (int i = 0; i < 8; ++i) {
            const int q = tid + 256 * i;          // 2048 16B chunks
            const int ch = q >> 4, mg = q & 15;
            bf16x8 v = *(const bf16x8*)(smem + ch * 128 + ((mg ^ (ch & 15)) << 3));
            *(bf16x8*)(Vt + (size_t)(cc0 + ch) * M + m0 + mg * 8) = v;
        }
    } else {
        __hip_bfloat16* dst = sel == 0 ? Qo : Ko;
        const float* bptr   = sel == 0 ? bq : bk;
        const float sc      = sel == 0 ? QSCALE : 1.0f;
        #pragma unroll
        for (int ni = 0; ni < 4; ++ni) {
            const int cc = (n0 + wc * 64 + ni * 16 + l15) & 1023;
            const float bias = bptr[cc];
            #pragma unroll
            for (int mi = 0; mi < 4; ++mi) {
                const int row = m0 + wr * 64 + mi * 16 + quad * 4;
                #pragma unroll
                for (int r = 0; r < 4; ++r)
                    dst[(size_t)(row + r) * 1024 + cc] =
                        __float2bfloat16((acc[mi][ni][r] + bias) * sc);
            }
        }
    }
}

// ---------------- out-proj GEMM (fp32 out), 64x128 tile, BK=64 ----------------
__global__ __launch_bounds__(256) void gemm_out_f32(
    const __hip_bfloat16* __restrict__ A,
    const __hip_bfloat16* __restrict__ B,
    const float* __restrict__ bias,
    float* __restrict__ Cf,
    int M, int N, int K)
{
    __shared__ __align__(16) __hip_bfloat16 As[64 * 64];
    __shared__ __align__(16) __hip_bfloat16 Bs[128 * 64];

    const int tid  = threadIdx.x;
    const int lane = tid & 63;
    const int wave = tid >> 6;
    const int l15  = lane & 15;
    const int quad = lane >> 4;
    const int m0 = blockIdx.x * 64;
    const int n0 = blockIdx.y * 128;
    const int wr = wave >> 1, wc = wave & 1;   // wave tile: 32 x 64

    f32x4 acc[2][4] = {};

    int srow[4], scol[4];
    #pragma unroll
    for (int i = 0; i < 4; ++i) {
        const int c = tid + 256 * i;
        srow[i] = c >> 3;
        scol[i] = ((c & 7) ^ (srow[i] & 7)) * 8;
    }

    for (int k0 = 0; k0 < K; k0 += 64) {
        __syncthreads();
        #pragma unroll
        for (int i = 0; i < 2; ++i)
            async_load16(A + (size_t)(m0 + srow[i]) * K + k0 + scol[i],
                         As + (size_t)(tid + 256 * i) * 8);
        #pragma unroll
        for (int i = 0; i < 4; ++i)
            async_load16(B + (size_t)(n0 + srow[i]) * K + k0 + scol[i],
                         Bs + (size_t)(tid + 256 * i) * 8);
        __syncthreads();

        #pragma unroll
        for (int kd = 0; kd < 2; ++kd) {
            bf16x8 af[2], bfr[4];
            #pragma unroll
            for (int mi = 0; mi < 2; ++mi) {
                const int row = wr * 32 + mi * 16 + l15;
                af[mi] = *(const bf16x8*)(
                    As + row * 64 + (((kd * 4 + quad) ^ (row & 7)) << 3));
            }
            #pragma unroll
            for (int ni = 0; ni < 4; ++ni) {
                const int row = wc * 64 + ni * 16 + l15;
                bfr[ni] = *(const bf16x8*)(
                    Bs + row * 64 + (((kd * 4 + quad) ^ (row & 7)) << 3));
            }
            #pragma unroll
            for (int mi = 0; mi < 2; ++mi)
                #pragma unroll
                for (int ni = 0; ni < 4; ++ni)
                    acc[mi][ni] = MFMA_BF16(af[mi], bfr[ni], acc[mi][ni], 0, 0, 0);
        }
    }

    #pragma unroll
    for (int ni = 0; ni < 4; ++ni) {
        const int col = n0 + wc * 64 + ni * 16 + l15;
        const float bv = bias[col];
        #pragma unroll
        for (int mi = 0; mi < 2; ++mi) {
            const int row = m0 + wr * 32 + mi * 16 + quad * 4;
            #pragma unroll
            for (int r = 0; r < 4; ++r)
                Cf[(size_t)(row + r) * N + col] = acc[mi][ni][r] + bv;
        }
    }
}

// ---------------- flash attention: balanced pair + quarter-split ----------------
// 256-row q-tiles (16 tiles). Block = (pair j, quarter s, head h): runs tile j's
// quarter-s key range (j+1 iters) then tile (15-j)'s quarter-s range (16-j iters)
// sequentially — exactly 17 iters per block, perfectly uniform grid.
// 8 waves x 32 q-rows; 64-key blocks, dbuf staging (16 KB/iter serves 8 wave-iters).
// S^T = K.Q^T with key labeling key(sb,m)=32(sb&1)+8(m>>2)+4(sb>>1)+(m&3) so the
// S^T C-layout regs ARE the P B-frags for O^T = V^T.P^T (P never leaves regs).
// Partials (unnormalized bf16 O, fp32 l) written per quarter; merged by merge_y.
// NO device-scope fences/atomics in-kernel: R9 showed __threadfence() costs ~8x
// (per-XCD L2 writeback serializes the whole pipeline).
__global__ __launch_bounds__(512, 4) void attn_causal(
    const __hip_bfloat16* __restrict__ Q,
    const __hip_bfloat16* __restrict__ K,
    const __hip_bfloat16* __restrict__ Vt,
    __hip_bfloat16* __restrict__ PoB,   // [4][T*C]
    float* __restrict__ PlB,            // [4][16*T]
    int T, int C)
{
    const int h  = blockIdx.y;
    const int bx = blockIdx.x;          // [0,32)
    const int j  = bx & 7;              // pair index
    const int sq = bx >> 3;             // quarter [0,4)
    const int tid  = threadIdx.x;
    const int w    = tid >> 6;          // wave [0,8)
    const int lane = tid & 63;
    const int l15  = lane & 15;
    const int quad = lane >> 4;

    const size_t TCs = (size_t)T * C;
    const size_t HT  = (size_t)T * 16;
    __hip_bfloat16* Po = PoB + (size_t)sq * TCs;
    float* Pl = PlB + (size_t)sq * HT;

    const int len1 = j + 1, len2 = 16 - j;
    const int tile1 = j,    tile2 = 15 - j;
    const int kb1 = len1 * sq, kb2 = len2 * sq;   // quarter starts

    __shared__ __align__(16) __hip_bfloat16 Ks[2][64 * 64];
    __shared__ __align__(16) __hip_bfloat16 Vts[2][64 * 64];

    const int r0 = tid >> 3, g0 = ((tid & 7) ^ (r0 & 7)) * 8;
    const __hip_bfloat16* Kg0 = K + (size_t)sig(r0) * C + h * 64 + g0;
    const __hip_bfloat16* Vg0 = Vt + (size_t)(h * 64 + r0) * T + g0;

    int koff[2][4], voff[2][4];
    #pragma unroll
    for (int kd = 0; kd < 2; ++kd)
        #pragma unroll
        for (int sb = 0; sb < 4; ++sb) {
            const int kappa = 32 * (sb & 1) + 8 * (l15 >> 2) + 4 * (sb >> 1) + (l15 & 3);
            const int rho = sig(kappa);
            koff[kd][sb] = rho * 64 + (((kd * 4 + quad) ^ (rho & 7)) << 3);
        }
    #pragma unroll
    for (int kk = 0; kk < 2; ++kk)
        #pragma unroll
        for (int db = 0; db < 4; ++db) {
            const int vrow = db * 16 + l15;
            voff[kk][db] = vrow * 64 + (((kk * 4 + quad) ^ (vrow & 7)) << 3);
        }

    bf16x8 ones;
    #pragma unroll
    for (int jj = 0; jj < 8; ++jj) ones[jj] = (__bf16)1.0f;

    int qbase = tile1 * 256 + w * 32;
    bf16x8 aq[2][2];
    #pragma unroll
    for (int rb = 0; rb < 2; ++rb)
        #pragma unroll
        for (int kd = 0; kd < 2; ++kd)
            aq[rb][kd] = *(const bf16x8*)(
                Q + (size_t)(qbase + rb * 16 + l15) * C + h * 64 + kd * 32 + quad * 8);

    f32x4 o[2][4] = {};
    f32x4 lacc[2] = {};

    {
        const size_t so = (size_t)kb1 << 6;
        async_load16(Kg0 + so * C, &Ks[0][tid * 8]);
        async_load16(Vg0 + so, &Vts[0][tid * 8]);
    }

    for (int it = 0; it < 17; ++it) {
        const int kb = (it < len1) ? (kb1 + it) : (kb2 + it - len1);
        const int s0 = kb << 6;
        __syncthreads();          // drain DMA + barrier: buf[it&1] ready
        const int cur = it & 1;
        if (it + 1 < 17) {
            const int kbn = (it + 1 < len1) ? (kb1 + it + 1) : (kb2 + it + 1 - len1);
            const size_t so = (size_t)kbn << 6;
            async_load16(Kg0 + so * C, &Ks[cur ^ 1][tid * 8]);
            async_load16(Vg0 + so, &Vts[cur ^ 1][tid * 8]);
        }

        if (it == len1) {
            // flush phase-1 partials, switch to tile2
            #pragma unroll
            for (int rb = 0; rb < 2; ++rb) {
                const int row = qbase + rb * 16 + l15;
                #pragma unroll
                for (int db = 0; db < 4; ++db) {
                    __hip_bfloat16 t[4];
                    #pragma unroll
                    for (int r = 0; r < 4; ++r)
                        t[r] = __float2bfloat16(o[rb][db][r]);
                    *(bf16x4*)(Po + (size_t)row * C + h * 64 + db * 16 + quad * 4)
                        = *(const bf16x4*)t;
                    o[rb][db] = (f32x4){0.f, 0.f, 0.f, 0.f};
                }
                if (quad == 0)
                    Pl[(size_t)h * T + row] = lacc[rb][0];
                lacc[rb] = (f32x4){0.f, 0.f, 0.f, 0.f};
            }
            qbase = tile2 * 256 + w * 32;
            #pragma unroll
            for (int rb = 0; rb < 2; ++rb)
                #pragma unroll
                for (int kd = 0; kd < 2; ++kd)
                    aq[rb][kd] = *(const bf16x8*)(
                        Q + (size_t)(qbase + rb * 16 + l15) * C + h * 64 + kd * 32 + quad * 8);
        }

        if (s0 <= qbase + 31) {   // wave-uniform skip
            f32x4 sv[2][4] = {};
            #pragma unroll
            for (int kd = 0; kd < 2; ++kd)
                #pragma unroll
                for (int sb = 0; sb < 4; ++sb) {
                    bf16x8 ak = *(const bf16x8*)(&Ks[cur][koff[kd][sb]]);
                    sv[0][sb] = MFMA_BF16(ak, aq[0][kd], sv[0][sb], 0, 0, 0);
                    sv[1][sb] = MFMA_BF16(ak, aq[1][kd], sv[1][sb], 0, 0, 0);
                }

            const bool diag = (s0 + 63 > qbase);  // wave-uniform
            bf16x8 bp[2][2];
            #pragma unroll
            for (int rb = 0; rb < 2; ++rb) {
                float pv[4][4];
                #pragma unroll
                for (int sb = 0; sb < 4; ++sb)
                    #pragma unroll
                    for (int r = 0; r < 4; ++r)
                        pv[sb][r] = __builtin_amdgcn_exp2f(sv[rb][sb][r]);
                if (diag) {
                    const int thr = qbase + rb * 16 + l15 - s0 - 8 * quad;
                    #pragma unroll
                    for (int sb = 0; sb < 4; ++sb)
                        #pragma unroll
                        for (int r = 0; r < 4; ++r) {
                            const int c = 32 * (sb & 1) + 4 * (sb >> 1) + r;
                            pv[sb][r] = (c <= thr) ? pv[sb][r] : 0.f;
                        }
                }
                #pragma unroll
                for (int kk = 0; kk < 2; ++kk) {
                    union { unsigned int u[4]; bf16x8 v; } pk;
                    pk.u[0] = pack_bf16_trunc(pv[kk][0], pv[kk][1]);
                    pk.u[1] = pack_bf16_trunc(pv[kk][2], pv[kk][3]);
                    pk.u[2] = pack_bf16_trunc(pv[kk + 2][0], pv[kk + 2][1]);
                    pk.u[3] = pack_bf16_trunc(pv[kk + 2][2], pv[kk + 2][3]);
                    bp[rb][kk] = pk.v;
                }
            }

            // l += 1^T . P^T  (matrix pipe)
            lacc[0] = MFMA_BF16(ones, bp[0][0], lacc[0], 0, 0, 0);
            lacc[0] = MFMA_BF16(ones, bp[0][1], lacc[0], 0, 0, 0);
            lacc[1] = MFMA_BF16(ones, bp[1][0], lacc[1], 0, 0, 0);
            lacc[1] = MFMA_BF16(ones, bp[1][1], lacc[1], 0, 0, 0);

            // O^T += V^T . P^T
            #pragma unroll
            for (int kk = 0; kk < 2; ++kk)
                #pragma unroll
                for (int db = 0; db < 4; ++db) {
                    bf16x8 av = *(const bf16x8*)(&Vts[cur][voff[kk][db]]);
                    o[0][db] = MFMA_BF16(av, bp[0][kk], o[0][db], 0, 0, 0);
                    o[1][db] = MFMA_BF16(av, bp[1][kk], o[1][db], 0, 0, 0);
                }
        }
    }

    // final flush (tile2)
    #pragma unroll
    for (int rb = 0; rb < 2; ++rb) {
        const int row = qbase + rb * 16 + l15;
        #pragma unroll
        for (int db = 0; db < 4; ++db) {
            __hip_bfloat16 t[4];
            #pragma unroll
            for (int r = 0; r < 4; ++r)
                t[r] = __float2bfloat16(o[rb][db][r]);
            *(bf16x4*)(Po + (size_t)row * C + h * 64 + db * 16 + quad * 4)
                = *(const bf16x4*)t;
        }
        if (quad == 0)
            Pl[(size_t)h * T + row] = lacc[rb][0];
    }
}

// Y = (sum_z Po[z]) / (sum_z Pl[z]), bf16 out. 8 elems/thread.
__global__ __launch_bounds__(256) void merge_y(
    const __hip_bfloat16* __restrict__ PoB, const float* __restrict__ PlB,
    __hip_bfloat16* __restrict__ Y, int T, int C)
{
    const size_t i = ((size_t)blockIdx.x * 256 + threadIdx.x) * 8;
    const int row = (int)(i / C);
    const int h   = ((int)(i % C)) >> 6;
    const size_t TC = (size_t)T * C;
    const size_t HT = (size_t)T * 16;
    float acc[8] = {};
    float l = 0.f;
    #pragma unroll
    for (int z = 0; z < 4; ++z) {
        bf16x8 a = *(const bf16x8*)(PoB + z * TC + i);
        #pragma unroll
        for (int r = 0; r < 8; ++r)
            acc[r] += (float)(((const __bf16*)&a)[r]);
        l += PlB[z * HT + (size_t)h * T + row];
    }
    const float inv = 1.0f / l;
    __hip_bfloat16 t[8];
    #pragma unroll
    for (int r = 0; r < 8; ++r)
        t[r] = __float2bfloat16(acc[r] * inv);
    *(bf16x8*)(Y + i) = *(const bf16x8*)t;
}

extern "C" void kernel_launch(void* const* d_in, const int* in_sizes, int n_in,
                              void* d_out, int out_size, void* d_ws, size_t ws_size,
                              hipStream_t stream)
{
    const float* x  = (const float*)d_in[0];
    const float* Wq = (const float*)d_in[1];
    const float* bq = (const float*)d_in[2];
    const float* Wk = (const float*)d_in[3];
    const float* bk = (const float*)d_in[4];
    const float* Wv = (const float*)d_in[5];
    const float* bv = (const float*)d_in[6];
    const float* Wp = (const float*)d_in[7];
    const float* bp = (const float*)d_in[8];

    const int C = 1024;
    const int T = in_sizes[0] / C;   // 4096
    const int H = 16;
    const size_t TC = (size_t)T * C;
    const size_t CC = (size_t)C * C;

    // ws (bf16 elems): xb | W4 | Q | K | Vt | Po[4] | Pl[4] (f32)
    __hip_bfloat16* xb  = (__hip_bfloat16*)d_ws;
    __hip_bfloat16* Wqb = xb + TC;
    __hip_bfloat16* Wkb = Wqb + CC;
    __hip_bfloat16* Wvb = Wkb + CC;
    __hip_bfloat16* Wpb = Wvb + CC;
    __hip_bfloat16* Qw  = Wpb + CC;
    __hip_bfloat16* Kw  = Qw + TC;
    __hip_bfloat16* Vtw = Kw + TC;
    __hip_bfloat16* PoB = Vtw + TC;          // 4 * TC bf16
    float* PlB = (float*)(PoB + 4 * TC);     // 4 * 16*T fp32
    __hip_bfloat16* Yw  = xb;                // alias: x dead after QKV GEMM
    float* out = (float*)d_out;

    convert_all<<<(int)(TC / 2048 + 4 * CC / 2048), 256, 0, stream>>>(
        x, Wq, Wk, Wv, Wp, xb, Wqb, Wkb, Wvb, Wpb, (int)TC, (int)CC);

    gemm_qkv<<<dim3(T / 128, 3072 / 128), 256, 0, stream>>>(
        xb, Wqb, bq, bk, bv, Qw, Kw, Vtw, T, C);

    attn_causal<<<dim3(32, H), 512, 0, stream>>>(
        Qw, Kw, Vtw, PoB, PlB, T, C);

    merge_y<<<(int)(TC / 8 / 256), 256, 0, stream>>>(
        PoB, PlB, Yw, T, C);

    gemm_out_f32<<<dim3(T / 64, C / 128), 256, 0, stream>>>(
        Yw, Wpb, bp, out, T, C, C);
}